// Round 1
// 503.193 us; speedup vs baseline: 1.2480x; 1.2480x over previous
//
#include <hip/hip_runtime.h>
#include <hip/hip_bf16.h>
#include <cstdint>

typedef __bf16 bf16_t;
typedef bf16_t bf16x8 __attribute__((ext_vector_type(8)));
typedef float f32x4 __attribute__((ext_vector_type(4)));
typedef float f32x16 __attribute__((ext_vector_type(16)));
typedef unsigned u32x4 __attribute__((ext_vector_type(4)));

#define MFMA16(a, b, c) __builtin_amdgcn_mfma_f32_16x16x32_bf16(a, b, c, 0, 0, 0)
#define MFMA32(a, b, c) __builtin_amdgcn_mfma_f32_32x32x16_bf16(a, b, c, 0, 0, 0)

constexpr int LDK = 72;  // 64 + 8 pad (gemm128 tiles)

// 0.125 (attn scale) * log2(e): folded into Q columns of w_qkv at transpose.
#define QSCALE 0.1803368801f
#define LOG2E 1.44269504f

__global__ void zero_out(unsigned short* __restrict__ out, long n) {
    long i = (long)blockIdx.x * 256 + threadIdx.x;
    if (i < n) out[i] = 0;
}

__global__ void detect_dtype(const unsigned* __restrict__ x,
                             int* __restrict__ flag) {
    if (threadIdx.x == 0 && blockIdx.x == 0) {
        int cnt = 0;
        for (int i = 0; i < 1024; ++i) {
            unsigned e = (x[i] >> 7) & 0xFF;
            cnt += (e > 100 && e < 150) ? 1 : 0;
        }
        *flag = (cnt > 512) ? 1 : 0;
    }
}

// Transpose; rows of the OUTPUT with index < scale_rows get scaled by QSCALE
// (used to fold attn scale * log2e into the Q columns of w_qkv).
__global__ void transpose_flex(const void* __restrict__ in,
                               bf16_t* __restrict__ out, int R, int C,
                               const int* __restrict__ flagp, int scale_rows) {
    const int fl = *flagp;
    __shared__ bf16_t tile[32][33];
    int c0 = blockIdx.x * 32, r0 = blockIdx.y * 32;
    int x = threadIdx.x, y = threadIdx.y;  // 32 x 8
#pragma unroll
    for (int i = 0; i < 4; ++i) {
        long idx = (long)(r0 + y + 8 * i) * C + c0 + x;
        float fv = fl ? (float)((const bf16_t*)in)[idx]
                      : ((const float*)in)[idx];
        if (c0 + x < scale_rows) fv *= QSCALE;
        tile[y + 8 * i][x] = (bf16_t)fv;
    }
    __syncthreads();
#pragma unroll
    for (int i = 0; i < 4; ++i)
        out[(long)(c0 + y + 8 * i) * R + r0 + x] = tile[x][y + 8 * i];
}

// ---------------------------------------------------------------------------
// Bias pre-permuted into the 32x32 MFMA C-layout so flash reads it as two
// coalesced dwordx4 loads per lane per 32-j tile (no LDS, no scalar gathers).
// perm[h][qb][jt][lane][reg] = log2e * table[relidx[i*1024+j]][h]
//   i = qb*32 + (lane&31); j = jt*32 + (reg&3) + 8*(reg>>2) + 4*(lane>>5)
// ---------------------------------------------------------------------------
__global__ __launch_bounds__(256) void build_bias_perm(
    const int* __restrict__ rel_index, const void* __restrict__ bias_table,
    bf16_t* __restrict__ perm, const int* __restrict__ flagp) {
    const int fl = *flagp;
    const int jt = blockIdx.x;  // 0..31
    const int qb = blockIdx.y;  // 0..31
    const int t = threadIdx.x;
    const int lane = t & 63;
    const int h = (t >> 6) + 4 * blockIdx.z;  // 0..7
    const int i = qb * 32 + (lane & 31);
    const int hi = lane >> 5;
    bf16_t out[16];
#pragma unroll
    for (int r = 0; r < 16; ++r) {
        int j = jt * 32 + (r & 3) + 8 * (r >> 2) + 4 * hi;
        int ridx = rel_index[i * 1024 + j];
        ridx = ridx < 0 ? 0 : (ridx > 44 ? 44 : ridx);
        float bv = fl ? (float)((const bf16_t*)bias_table)[ridx * 8 + h]
                      : ((const float*)bias_table)[ridx * 8 + h];
        out[r] = (bf16_t)(bv * LOG2E);
    }
    long off = (((long)(h * 32 + qb) * 32 + jt) << 10) + lane * 16;
    *(uint4*)&perm[off] = *(uint4*)&out[0];
    *(uint4*)&perm[off + 8] = *(uint4*)&out[8];
}

// C[(c_row0+m)][n] = sum_k A[(a_row0+m)][k] * Bt[n][k]  (+ bias[n])
template <bool AFLEX, bool BIAS, bool OUTFLEX>
__global__ __launch_bounds__(256) void gemm128(
    const void* __restrict__ A, const bf16_t* __restrict__ Bt, int K, int lda,
    long a_row0, void* __restrict__ C, int ldc, long c_row0,
    const void* __restrict__ bias, const int* __restrict__ flagp) {
    const int fl = *flagp;
    __shared__ bf16_t a_lds[128 * LDK];
    __shared__ bf16_t b_lds[128 * LDK];
    int t = threadIdx.x;
    int wave = t >> 6, lane = t & 63;
    int m16 = lane & 15, quad = lane >> 4;
    int wr = wave >> 1, wc = wave & 1;
    long m0 = (long)blockIdx.y * 128;
    int n0 = blockIdx.x * 128;

    f32x4 acc[4][4] = {};

    for (int ks = 0; ks < K; ks += 64) {
#pragma unroll
        for (int i = 0; i < 4; ++i) {
            int c = t + 256 * i;
            int row = c >> 3;
            int kc = (c & 7) << 3;
            bf16x8 av;
            if (AFLEX && !fl) {
                const float* Af = (const float*)A;
                long base = (a_row0 + m0 + row) * (long)lda + ks + kc;
                f32x4 lo = *(const f32x4*)&Af[base];
                f32x4 hi = *(const f32x4*)&Af[base + 4];
#pragma unroll
                for (int e = 0; e < 4; ++e) {
                    av[e] = (bf16_t)lo[e];
                    av[e + 4] = (bf16_t)hi[e];
                }
            } else {
                av = *(const bf16x8*)&(
                    (const bf16_t*)A)[(a_row0 + m0 + row) * (long)lda + ks + kc];
            }
            *(bf16x8*)&a_lds[row * LDK + kc] = av;
            *(bf16x8*)&b_lds[row * LDK + kc] =
                *(const bf16x8*)&Bt[(long)(n0 + row) * K + ks + kc];
        }
        __syncthreads();
#pragma unroll
        for (int kf = 0; kf < 2; ++kf) {
            bf16x8 af[4], bfr[4];
#pragma unroll
            for (int mb = 0; mb < 4; ++mb)
                af[mb] = *(const bf16x8*)&a_lds[(wr * 64 + mb * 16 + m16) * LDK +
                                                kf * 32 + quad * 8];
#pragma unroll
            for (int nb = 0; nb < 4; ++nb)
                bfr[nb] = *(const bf16x8*)&b_lds[(wc * 64 + nb * 16 + m16) * LDK +
                                                 kf * 32 + quad * 8];
#pragma unroll
            for (int mb = 0; mb < 4; ++mb)
#pragma unroll
                for (int nb = 0; nb < 4; ++nb)
                    acc[mb][nb] = MFMA16(af[mb], bfr[nb], acc[mb][nb]);
        }
        __syncthreads();
    }

#pragma unroll
    for (int mb = 0; mb < 4; ++mb) {
#pragma unroll
        for (int nb = 0; nb < 4; ++nb) {
            int col = n0 + wc * 64 + nb * 16 + m16;
#pragma unroll
            for (int r = 0; r < 4; ++r) {
                long row = m0 + wr * 64 + mb * 16 + quad * 4 + r;
                float v = acc[mb][nb][r];
                if (BIAS) {
                    float bb = fl ? (float)((const bf16_t*)bias)[col]
                                  : ((const float*)bias)[col];
                    v += bb;
                }
                long off = (c_row0 + row) * (long)ldc + col;
                if (OUTFLEX && !fl)
                    ((float*)C)[off] = v;
                else
                    ((bf16_t*)C)[off] = (bf16_t)v;
            }
        }
    }
}

// ---------------------------------------------------------------------------
// Flash attention v2: swapped-operand 32x32x16 MFMA, lane-local softmax.
// 4 waves x 32 q-rows each (128 q/block), KVBLK=64 double-buffered,
// XOR-swizzled K and V^T tiles, bias from pre-permuted table (no LDS),
// P repacked in-register via v_cvt_pk_bf16_f32 + v_permlane32_swap_b32.
// Q columns pre-scaled by 0.125*log2e; bias pre-scaled by log2e; exp2 domain.
// ---------------------------------------------------------------------------
__global__ __launch_bounds__(256) void flash_attn2(
    bf16_t* __restrict__ qkv, const bf16_t* __restrict__ bias_perm) {
    __shared__ bf16_t k_lds[2][64 * 64];
    __shared__ bf16_t v_lds[2][64 * 64];

    const int t = threadIdx.x;
    const int lane = t & 63, wave = t >> 6;
    const int l31 = lane & 31, hi = lane >> 5;
    const int h = blockIdx.y, b = blockIdx.z;
    bf16_t* base = qkv + (long)b * 1024 * 1536;
    bf16_t* qb = base + h * 64;
    const bf16_t* kb = base + 512 + h * 64;
    const bf16_t* vb = base + 1024 + h * 64;
    const int qblk = blockIdx.x * 4 + wave;  // 0..31
    const int q0w = qblk * 32;
    const bf16_t* bp = bias_perm + (((long)(h * 32 + qblk)) << 15) + lane * 16;

    // Q fragments (already scaled): B-operand rows = q
    bf16x8 qf[4];
#pragma unroll
    for (int s = 0; s < 4; ++s)
        qf[s] = *(const bf16x8*)&qb[(long)(q0w + l31) * 1536 + s * 16 + hi * 8];

    f32x16 oacc0 = {}, oacc1 = {};
    float mrun = -1e30f, lrun = 0.f;

    const int sr0 = t >> 3, sg0 = t & 7;  // staging: row 0..31, granule 0..7
    const int sr1 = sr0 + 32;

    {  // prologue: stage tile 0
        bf16x8 k0 = *(const bf16x8*)&kb[(long)sr0 * 1536 + sg0 * 8];
        bf16x8 k1 = *(const bf16x8*)&kb[(long)sr1 * 1536 + sg0 * 8];
        bf16x8 v0 = *(const bf16x8*)&vb[(long)sr0 * 1536 + sg0 * 8];
        bf16x8 v1 = *(const bf16x8*)&vb[(long)sr1 * 1536 + sg0 * 8];
        *(bf16x8*)&k_lds[0][sr0 * 64 + ((sg0 ^ (sr0 & 7)) << 3)] = k0;
        *(bf16x8*)&k_lds[0][sr1 * 64 + ((sg0 ^ (sr1 & 7)) << 3)] = k1;
#pragma unroll
        for (int e = 0; e < 8; ++e) {
            int d0 = sg0 * 8 + e;
            v_lds[0][d0 * 64 + (((sr0 >> 3) ^ (d0 & 7)) << 3) + (sr0 & 7)] = v0[e];
            v_lds[0][d0 * 64 + (((sr1 >> 3) ^ (d0 & 7)) << 3) + (sr1 & 7)] = v1[e];
        }
    }
    __syncthreads();

    for (int tt = 0; tt < 16; ++tt) {
        const int cur = tt & 1;
        bf16x8 kn0 = {}, kn1 = {}, vn0 = {}, vn1 = {};
        if (tt < 15) {  // issue next tile's global loads early (latency hiding)
            long j0n = (long)(tt + 1) * 64;
            kn0 = *(const bf16x8*)&kb[(j0n + sr0) * 1536 + sg0 * 8];
            kn1 = *(const bf16x8*)&kb[(j0n + sr1) * 1536 + sg0 * 8];
            vn0 = *(const bf16x8*)&vb[(j0n + sr0) * 1536 + sg0 * 8];
            vn1 = *(const bf16x8*)&vb[(j0n + sr1) * 1536 + sg0 * 8];
        }
        // bias for both 32-j substeps: coalesced dwordx4 loads
        const bf16_t* bt = bp + ((long)tt << 11);
        uint4 bv[4];
        bv[0] = *(const uint4*)(bt);
        bv[1] = *(const uint4*)(bt + 8);
        bv[2] = *(const uint4*)(bt + 1024);
        bv[3] = *(const uint4*)(bt + 1024 + 8);

#pragma unroll
        for (int js = 0; js < 2; ++js) {
            // ---- S^T = K Q^T : lane owns q-row (col = l31) ----
            f32x16 s = {};
            const int krow = js * 32 + l31;
#pragma unroll
            for (int st = 0; st < 4; ++st) {
                bf16x8 kf = *(const bf16x8*)&k_lds[cur][krow * 64 +
                             (((st * 2 + hi) ^ (krow & 7)) << 3)];
                s = MFMA32(kf, qf[st], s);
            }
            // ---- + bias (already log2e-scaled, layout-matched) ----
            bf16_t bb[16];
            *(uint4*)&bb[0] = bv[2 * js];
            *(uint4*)&bb[8] = bv[2 * js + 1];
            float sv[16];
#pragma unroll
            for (int r = 0; r < 16; ++r) sv[r] = s[r] + (float)bb[r];
            // ---- row max: in-lane tree + one cross-half swap ----
            float mx = sv[0];
#pragma unroll
            for (int r = 1; r < 16; ++r) mx = fmaxf(mx, sv[r]);
            {
                float o0 = mx, o1 = mx;
                asm("" : "+v"(o1));
                asm("v_permlane32_swap_b32 %0, %1" : "+v"(o0), "+v"(o1));
                mx = fmaxf(o0, o1);
            }
            // ---- defer-max rescale (THR=11 in log2 units ~ e^7.6) ----
            if (!__all(mx <= mrun + 11.0f)) {
                float mnew = fmaxf(mrun, mx);
                float al = __builtin_amdgcn_exp2f(mrun - mnew);
                mrun = mnew;
                lrun *= al;
#pragma unroll
                for (int r = 0; r < 16; ++r) {
                    oacc0[r] *= al;
                    oacc1[r] *= al;
                }
            }
            // ---- P = 2^(S-m), row sum ----
            float s0 = 0.f, s1 = 0.f, s2 = 0.f, s3 = 0.f;
#pragma unroll
            for (int r = 0; r < 16; ++r) {
                sv[r] = __builtin_amdgcn_exp2f(sv[r] - mrun);
                if ((r & 3) == 0) s0 += sv[r];
                else if ((r & 3) == 1) s1 += sv[r];
                else if ((r & 3) == 2) s2 += sv[r];
                else s3 += sv[r];
            }
            float rs = (s0 + s1) + (s2 + s3);
            {
                float o0 = rs, o1 = rs;
                asm("" : "+v"(o1));
                asm("v_permlane32_swap_b32 %0, %1" : "+v"(o0), "+v"(o1));
                rs = o0 + o1;
            }
            lrun += rs;
            // ---- repack P^T (C-layout) -> PV A-fragments, in-register ----
            unsigned dw[8];
#pragma unroll
            for (int g = 0; g < 4; ++g) {
                unsigned da, db;
                asm("v_cvt_pk_bf16_f32 %0, %1, %2"
                    : "=v"(da) : "v"(sv[4 * g]), "v"(sv[4 * g + 1]));
                asm("v_cvt_pk_bf16_f32 %0, %1, %2"
                    : "=v"(db) : "v"(sv[4 * g + 2]), "v"(sv[4 * g + 3]));
                dw[2 * g] = da;
                dw[2 * g + 1] = db;
            }
#pragma unroll
            for (int kk = 0; kk < 2; ++kk) {
                asm("v_permlane32_swap_b32 %0, %1"
                    : "+v"(dw[4 * kk + 0]), "+v"(dw[4 * kk + 2]));
                asm("v_permlane32_swap_b32 %0, %1"
                    : "+v"(dw[4 * kk + 1]), "+v"(dw[4 * kk + 3]));
            }
            // ---- O += P V (O direct: rows=q, cols=d) ----
#pragma unroll
            for (int kk = 0; kk < 2; ++kk) {
                u32x4 uv;
                uv[0] = dw[4 * kk + 0];
                uv[1] = dw[4 * kk + 1];
                uv[2] = dw[4 * kk + 2];
                uv[3] = dw[4 * kk + 3];
                bf16x8 pa = __builtin_bit_cast(bf16x8, uv);
#pragma unroll
                for (int db2 = 0; db2 < 2; ++db2) {
                    const int vrow = db2 * 32 + l31;
                    bf16x8 vf = *(const bf16x8*)&v_lds[cur][vrow * 64 +
                                 (((js * 4 + kk * 2 + hi) ^ (vrow & 7)) << 3)];
                    if (db2 == 0)
                        oacc0 = MFMA32(pa, vf, oacc0);
                    else
                        oacc1 = MFMA32(pa, vf, oacc1);
                }
            }
        }  // js
        if (tt < 15) {  // write staged regs into the other buffer
            const int nb = cur ^ 1;
            *(bf16x8*)&k_lds[nb][sr0 * 64 + ((sg0 ^ (sr0 & 7)) << 3)] = kn0;
            *(bf16x8*)&k_lds[nb][sr1 * 64 + ((sg0 ^ (sr1 & 7)) << 3)] = kn1;
#pragma unroll
            for (int e = 0; e < 8; ++e) {
                int d0 = sg0 * 8 + e;
                v_lds[nb][d0 * 64 + (((sr0 >> 3) ^ (d0 & 7)) << 3) + (sr0 & 7)] =
                    vn0[e];
                v_lds[nb][d0 * 64 + (((sr1 >> 3) ^ (d0 & 7)) << 3) + (sr1 & 7)] =
                    vn1[e];
            }
        }
        __syncthreads();
    }

    // ---- epilogue: O[i][d] / l[i]; 1/l broadcast via ds_bpermute ----
    float linv = 1.0f / lrun;
#pragma unroll
    for (int r = 0; r < 16; ++r) {
        int row = (r & 3) + 8 * (r >> 2) + 4 * hi;
        float lr = __int_as_float(
            __builtin_amdgcn_ds_bpermute(row << 2, __float_as_int(linv)));
        qb[(long)(q0w + row) * 1536 + l31] = (bf16_t)(oacc0[r] * lr);
        qb[(long)(q0w + row) * 1536 + 32 + l31] = (bf16_t)(oacc1[r] * lr);
    }
}

extern "C" void kernel_launch(void* const* d_in, const int* in_sizes, int n_in,
                              void* d_out, int out_size, void* d_ws,
                              size_t ws_size, hipStream_t stream) {
    const void* x = nullptr;
    const void* w_qkv = nullptr;
    const void* bias_table = nullptr;
    const void* w_out = nullptr;
    const void* b_out = nullptr;
    const void* rel_raw = nullptr;
    for (int i = 0; i < n_in; ++i) {
        switch (in_sizes[i]) {
            case 16777216: x = d_in[i]; break;
            case 786432:  w_qkv = d_in[i]; break;
            case 360:     bias_table = d_in[i]; break;
            case 262144:  w_out = d_in[i]; break;
            case 512:     b_out = d_in[i]; break;
            case 1048576: rel_raw = d_in[i]; break;
            default: break;
        }
    }
    if (!x || !w_qkv || !bias_table || !w_out || !b_out || !rel_raw) {
        x = d_in[0]; w_qkv = d_in[1]; bias_table = d_in[2];
        w_out = d_in[3]; b_out = d_in[4]; rel_raw = d_in[5];
    }
    const int* rel_index = (const int*)rel_raw;

    char* ws = (char*)d_ws;
    bf16_t* wqkvT = (bf16_t*)ws;                           // 1,572,864 B
    bf16_t* woutT = (bf16_t*)(ws + 1572864);               // 524,288 B
    int* flag = (int*)(ws + 1572864 + 524288);             // 256 B slot
    bf16_t* rel_bias = (bf16_t*)(ws + 1572864 + 524288 + 256);  // 16 MiB perm
    const size_t fixed = 1572864 + 524288 + 256 + 16777216;
    bf16_t* qkv = (bf16_t*)(ws + fixed);
    const size_t per_batch = (size_t)1024 * 1536 * sizeof(bf16_t);  // 3 MiB

    if (ws_size < fixed + per_batch) {
        long n = (long)out_size;
        long nblk = (n + 255) / 256;
        if (nblk > 0)
            zero_out<<<(unsigned)nblk, 256, 0, stream>>>(
                (unsigned short*)d_out, n);
        return;
    }

    size_t avail = ws_size - fixed;
    int chunk = (int)(avail / per_batch);
    if (chunk > 32) chunk = 32;
    if (chunk < 1) chunk = 1;
    while (32 % chunk) --chunk;

    detect_dtype<<<1, 64, 0, stream>>>((const unsigned*)x, flag);
    transpose_flex<<<dim3(1536 / 32, 512 / 32), dim3(32, 8), 0, stream>>>(
        w_qkv, wqkvT, 512, 1536, flag, 512);  // scale Q columns
    transpose_flex<<<dim3(512 / 32, 512 / 32), dim3(32, 8), 0, stream>>>(
        w_out, woutT, 512, 512, flag, 0);
    build_bias_perm<<<dim3(32, 32, 2), 256, 0, stream>>>(
        rel_index, bias_table, rel_bias, flag);

    for (int b0 = 0; b0 < 32; b0 += chunk) {
        long row0 = (long)b0 * 1024;
        int mrows = chunk * 1024;
        gemm128<true, false, false>
            <<<dim3(1536 / 128, mrows / 128), 256, 0, stream>>>(
                x, wqkvT, 512, 512, row0, qkv, 1536, 0, nullptr, flag);
        flash_attn2<<<dim3(8, 8, chunk), 256, 0, stream>>>(qkv, rel_bias);
        gemm128<false, true, true>
            <<<dim3(512 / 128, mrows / 128), 256, 0, stream>>>(
                qkv, woutT, 512, 1536, 0, d_out, 512, row0, b_out, flag);
    }
}

// Round 2
// 474.165 us; speedup vs baseline: 1.3244x; 1.0612x over previous
//
#include <hip/hip_runtime.h>
#include <hip/hip_bf16.h>
#include <cstdint>

typedef __bf16 bf16_t;
typedef bf16_t bf16x8 __attribute__((ext_vector_type(8)));
typedef float f32x4 __attribute__((ext_vector_type(4)));
typedef float f32x16 __attribute__((ext_vector_type(16)));
typedef unsigned u32x4 __attribute__((ext_vector_type(4)));

#define MFMA16(a, b, c) __builtin_amdgcn_mfma_f32_16x16x32_bf16(a, b, c, 0, 0, 0)
#define MFMA32(a, b, c) __builtin_amdgcn_mfma_f32_32x32x16_bf16(a, b, c, 0, 0, 0)

// async global->LDS, 16B per lane (ladder step 3; compiler never auto-emits)
#define GLOAD_LDS16(g, l)                                                  \
    __builtin_amdgcn_global_load_lds(                                      \
        (const __attribute__((address_space(1))) unsigned*)(g),            \
        (__attribute__((address_space(3))) unsigned*)(l), 16, 0, 0)

constexpr int LDK = 72;  // 64 + 8 pad (legacy gemm128 fallback)

// 0.125 (attn scale) * log2(e): folded into Q columns of w_qkv at transpose.
#define QSCALE 0.1803368801f
#define LOG2E 1.44269504f

__global__ void zero_out(unsigned short* __restrict__ out, long n) {
    long i = (long)blockIdx.x * 256 + threadIdx.x;
    if (i < n) out[i] = 0;
}

__global__ void detect_dtype(const unsigned* __restrict__ x,
                             int* __restrict__ flag) {
    if (threadIdx.x == 0 && blockIdx.x == 0) {
        int cnt = 0;
        for (int i = 0; i < 1024; ++i) {
            unsigned e = (x[i] >> 7) & 0xFF;
            cnt += (e > 100 && e < 150) ? 1 : 0;
        }
        *flag = (cnt > 512) ? 1 : 0;
    }
}

// x (fp32 or bf16 per flag) -> x_bf (bf16), vectorized.  96 MB => ~15 us.
__global__ __launch_bounds__(256) void convert_x(const void* __restrict__ in,
                                                 bf16_t* __restrict__ out,
                                                 const int* __restrict__ flagp) {
    const int fl = *flagp;
    long i = ((long)blockIdx.x * 256 + threadIdx.x) * 8;
    if (fl) {
        *(bf16x8*)&out[i] = *(const bf16x8*)&((const bf16_t*)in)[i];
    } else {
        f32x4 lo = *(const f32x4*)&((const float*)in)[i];
        f32x4 hi = *(const f32x4*)&((const float*)in)[i + 4];
        bf16x8 v;
#pragma unroll
        for (int e = 0; e < 4; ++e) {
            v[e] = (bf16_t)lo[e];
            v[e + 4] = (bf16_t)hi[e];
        }
        *(bf16x8*)&out[i] = v;
    }
}

// Transpose; rows of the OUTPUT with index < scale_rows get scaled by QSCALE
// (used to fold attn scale * log2e into the Q columns of w_qkv).
__global__ void transpose_flex(const void* __restrict__ in,
                               bf16_t* __restrict__ out, int R, int C,
                               const int* __restrict__ flagp, int scale_rows) {
    const int fl = *flagp;
    __shared__ bf16_t tile[32][33];
    int c0 = blockIdx.x * 32, r0 = blockIdx.y * 32;
    int x = threadIdx.x, y = threadIdx.y;  // 32 x 8
#pragma unroll
    for (int i = 0; i < 4; ++i) {
        long idx = (long)(r0 + y + 8 * i) * C + c0 + x;
        float fv = fl ? (float)((const bf16_t*)in)[idx]
                      : ((const float*)in)[idx];
        if (c0 + x < scale_rows) fv *= QSCALE;
        tile[y + 8 * i][x] = (bf16_t)fv;
    }
    __syncthreads();
#pragma unroll
    for (int i = 0; i < 4; ++i)
        out[(long)(c0 + y + 8 * i) * R + r0 + x] = tile[x][y + 8 * i];
}

// ---------------------------------------------------------------------------
// Bias pre-permuted into the 32x32 MFMA C-layout so flash reads it as two
// coalesced dwordx4 loads per lane per 32-j tile (no LDS, no scalar gathers).
// perm[h][qb][jt][lane][reg] = log2e * table[relidx[i*1024+j]][h]
//   i = qb*32 + (lane&31); j = jt*32 + (reg&3) + 8*(reg>>2) + 4*(lane>>5)
// ---------------------------------------------------------------------------
__global__ __launch_bounds__(256) void build_bias_perm(
    const int* __restrict__ rel_index, const void* __restrict__ bias_table,
    bf16_t* __restrict__ perm, const int* __restrict__ flagp) {
    const int fl = *flagp;
    const int jt = blockIdx.x;  // 0..31
    const int qb = blockIdx.y;  // 0..31
    const int t = threadIdx.x;
    const int lane = t & 63;
    const int h = (t >> 6) + 4 * blockIdx.z;  // 0..7
    const int i = qb * 32 + (lane & 31);
    const int hi = lane >> 5;
    bf16_t out[16];
#pragma unroll
    for (int r = 0; r < 16; ++r) {
        int j = jt * 32 + (r & 3) + 8 * (r >> 2) + 4 * hi;
        int ridx = rel_index[i * 1024 + j];
        ridx = ridx < 0 ? 0 : (ridx > 44 ? 44 : ridx);
        float bv = fl ? (float)((const bf16_t*)bias_table)[ridx * 8 + h]
                      : ((const float*)bias_table)[ridx * 8 + h];
        out[r] = (bf16_t)(bv * LOG2E);
    }
    long off = (((long)(h * 32 + qb) * 32 + jt) << 10) + lane * 16;
    *(uint4*)&perm[off] = *(uint4*)&out[0];
    *(uint4*)&perm[off + 8] = *(uint4*)&out[8];
}

// ---------------------------------------------------------------------------
// m97-structure GEMM: bf16 A and Bt, global_load_lds (width=16) staging into
// linear [128][64] LDS, 2 barriers per K-step.
// C[(c_row0+m)][n] = sum_k A[(a_row0+m)][k] * Bt[n][k]  (+ bias[n])
// ---------------------------------------------------------------------------
template <bool BIAS, bool OUTFLEX>
__global__ __launch_bounds__(256) void gemm_lds(
    const bf16_t* __restrict__ A, const bf16_t* __restrict__ Bt, int K,
    int lda, long a_row0, void* __restrict__ C, int ldc, long c_row0,
    const void* __restrict__ bias, const int* __restrict__ flagp) {
    const int fl = *flagp;
    __shared__ bf16_t a_lds[128 * 64];
    __shared__ bf16_t b_lds[128 * 64];
    int t = threadIdx.x;
    int wave = t >> 6, lane = t & 63;
    int m16 = lane & 15, quad = lane >> 4;
    int wr = wave >> 1, wc = wave & 1;
    long m0 = (long)blockIdx.y * 128;
    int n0 = blockIdx.x * 128;

    // staging: 1024 16B-chunks per tile; chunk c -> row=c>>3, col=(c&7)*8.
    // wave-uniform LDS dest (lane-linear), per-lane global src.
    const int c_base = wave * 256 + lane;  // + i*64

    f32x4 acc[4][4] = {};

    for (int ks = 0; ks < K; ks += 64) {
#pragma unroll
        for (int i = 0; i < 4; ++i) {
            int c = c_base;  // wave*256 + i*64 + lane
            c = wave * 256 + i * 64 + lane;
            int row = c >> 3, kc = (c & 7) << 3;
            GLOAD_LDS16(&A[(a_row0 + m0 + row) * (long)lda + ks + kc],
                        &a_lds[row * 64 + kc]);
            GLOAD_LDS16(&Bt[(long)(n0 + row) * K + ks + kc],
                        &b_lds[row * 64 + kc]);
        }
        __syncthreads();
#pragma unroll
        for (int kf = 0; kf < 2; ++kf) {
            bf16x8 af[4], bfr[4];
#pragma unroll
            for (int mb = 0; mb < 4; ++mb)
                af[mb] = *(const bf16x8*)&a_lds[(wr * 64 + mb * 16 + m16) * 64 +
                                                kf * 32 + quad * 8];
#pragma unroll
            for (int nb = 0; nb < 4; ++nb)
                bfr[nb] = *(const bf16x8*)&b_lds[(wc * 64 + nb * 16 + m16) * 64 +
                                                 kf * 32 + quad * 8];
#pragma unroll
            for (int mb = 0; mb < 4; ++mb)
#pragma unroll
                for (int nb = 0; nb < 4; ++nb)
                    acc[mb][nb] = MFMA16(af[mb], bfr[nb], acc[mb][nb]);
        }
        __syncthreads();
    }

#pragma unroll
    for (int mb = 0; mb < 4; ++mb) {
#pragma unroll
        for (int nb = 0; nb < 4; ++nb) {
            int col = n0 + wc * 64 + nb * 16 + m16;
#pragma unroll
            for (int r = 0; r < 4; ++r) {
                long row = m0 + wr * 64 + mb * 16 + quad * 4 + r;
                float v = acc[mb][nb][r];
                if (BIAS) {
                    float bb = fl ? (float)((const bf16_t*)bias)[col]
                                  : ((const float*)bias)[col];
                    v += bb;
                }
                long off = (c_row0 + row) * (long)ldc + col;
                if (OUTFLEX && !fl)
                    ((float*)C)[off] = v;
                else
                    ((bf16_t*)C)[off] = (bf16_t)v;
            }
        }
    }
}

// Legacy register-staged flex GEMM (fallback when ws can't hold x_bf).
template <bool AFLEX, bool BIAS, bool OUTFLEX>
__global__ __launch_bounds__(256) void gemm128(
    const void* __restrict__ A, const bf16_t* __restrict__ Bt, int K, int lda,
    long a_row0, void* __restrict__ C, int ldc, long c_row0,
    const void* __restrict__ bias, const int* __restrict__ flagp) {
    const int fl = *flagp;
    __shared__ bf16_t a_lds[128 * LDK];
    __shared__ bf16_t b_lds[128 * LDK];
    int t = threadIdx.x;
    int wave = t >> 6, lane = t & 63;
    int m16 = lane & 15, quad = lane >> 4;
    int wr = wave >> 1, wc = wave & 1;
    long m0 = (long)blockIdx.y * 128;
    int n0 = blockIdx.x * 128;

    f32x4 acc[4][4] = {};

    for (int ks = 0; ks < K; ks += 64) {
#pragma unroll
        for (int i = 0; i < 4; ++i) {
            int c = t + 256 * i;
            int row = c >> 3;
            int kc = (c & 7) << 3;
            bf16x8 av;
            if (AFLEX && !fl) {
                const float* Af = (const float*)A;
                long base = (a_row0 + m0 + row) * (long)lda + ks + kc;
                f32x4 lo = *(const f32x4*)&Af[base];
                f32x4 hi = *(const f32x4*)&Af[base + 4];
#pragma unroll
                for (int e = 0; e < 4; ++e) {
                    av[e] = (bf16_t)lo[e];
                    av[e + 4] = (bf16_t)hi[e];
                }
            } else {
                av = *(const bf16x8*)&(
                    (const bf16_t*)A)[(a_row0 + m0 + row) * (long)lda + ks + kc];
            }
            *(bf16x8*)&a_lds[row * LDK + kc] = av;
            *(bf16x8*)&b_lds[row * LDK + kc] =
                *(const bf16x8*)&Bt[(long)(n0 + row) * K + ks + kc];
        }
        __syncthreads();
#pragma unroll
        for (int kf = 0; kf < 2; ++kf) {
            bf16x8 af[4], bfr[4];
#pragma unroll
            for (int mb = 0; mb < 4; ++mb)
                af[mb] = *(const bf16x8*)&a_lds[(wr * 64 + mb * 16 + m16) * LDK +
                                                kf * 32 + quad * 8];
#pragma unroll
            for (int nb = 0; nb < 4; ++nb)
                bfr[nb] = *(const bf16x8*)&b_lds[(wc * 64 + nb * 16 + m16) * LDK +
                                                 kf * 32 + quad * 8];
#pragma unroll
            for (int mb = 0; mb < 4; ++mb)
#pragma unroll
                for (int nb = 0; nb < 4; ++nb)
                    acc[mb][nb] = MFMA16(af[mb], bfr[nb], acc[mb][nb]);
        }
        __syncthreads();
    }

#pragma unroll
    for (int mb = 0; mb < 4; ++mb) {
#pragma unroll
        for (int nb = 0; nb < 4; ++nb) {
            int col = n0 + wc * 64 + nb * 16 + m16;
#pragma unroll
            for (int r = 0; r < 4; ++r) {
                long row = m0 + wr * 64 + mb * 16 + quad * 4 + r;
                float v = acc[mb][nb][r];
                if (BIAS) {
                    float bb = fl ? (float)((const bf16_t*)bias)[col]
                                  : ((const float*)bias)[col];
                    v += bb;
                }
                long off = (c_row0 + row) * (long)ldc + col;
                if (OUTFLEX && !fl)
                    ((float*)C)[off] = v;
                else
                    ((bf16_t*)C)[off] = (bf16_t)v;
            }
        }
    }
}

// ---------------------------------------------------------------------------
// Flash attention v2: swapped-operand 32x32x16 MFMA, lane-local softmax.
// ---------------------------------------------------------------------------
__global__ __launch_bounds__(256) void flash_attn2(
    bf16_t* __restrict__ qkv, const bf16_t* __restrict__ bias_perm) {
    __shared__ bf16_t k_lds[2][64 * 64];
    __shared__ bf16_t v_lds[2][64 * 64];

    const int t = threadIdx.x;
    const int lane = t & 63, wave = t >> 6;
    const int l31 = lane & 31, hi = lane >> 5;
    const int h = blockIdx.y, b = blockIdx.z;
    bf16_t* base = qkv + (long)b * 1024 * 1536;
    bf16_t* qb = base + h * 64;
    const bf16_t* kb = base + 512 + h * 64;
    const bf16_t* vb = base + 1024 + h * 64;
    const int qblk = blockIdx.x * 4 + wave;  // 0..31
    const int q0w = qblk * 32;
    const bf16_t* bp = bias_perm + (((long)(h * 32 + qblk)) << 15) + lane * 16;

    bf16x8 qf[4];
#pragma unroll
    for (int s = 0; s < 4; ++s)
        qf[s] = *(const bf16x8*)&qb[(long)(q0w + l31) * 1536 + s * 16 + hi * 8];

    f32x16 oacc0 = {}, oacc1 = {};
    float mrun = -1e30f, lrun = 0.f;

    const int sr0 = t >> 3, sg0 = t & 7;
    const int sr1 = sr0 + 32;

    {  // prologue: stage tile 0
        bf16x8 k0 = *(const bf16x8*)&kb[(long)sr0 * 1536 + sg0 * 8];
        bf16x8 k1 = *(const bf16x8*)&kb[(long)sr1 * 1536 + sg0 * 8];
        bf16x8 v0 = *(const bf16x8*)&vb[(long)sr0 * 1536 + sg0 * 8];
        bf16x8 v1 = *(const bf16x8*)&vb[(long)sr1 * 1536 + sg0 * 8];
        *(bf16x8*)&k_lds[0][sr0 * 64 + ((sg0 ^ (sr0 & 7)) << 3)] = k0;
        *(bf16x8*)&k_lds[0][sr1 * 64 + ((sg0 ^ (sr1 & 7)) << 3)] = k1;
#pragma unroll
        for (int e = 0; e < 8; ++e) {
            int d0 = sg0 * 8 + e;
            v_lds[0][d0 * 64 + (((sr0 >> 3) ^ (d0 & 7)) << 3) + (sr0 & 7)] = v0[e];
            v_lds[0][d0 * 64 + (((sr1 >> 3) ^ (d0 & 7)) << 3) + (sr1 & 7)] = v1[e];
        }
    }
    __syncthreads();

    for (int tt = 0; tt < 16; ++tt) {
        const int cur = tt & 1;
        bf16x8 kn0 = {}, kn1 = {}, vn0 = {}, vn1 = {};
        if (tt < 15) {
            long j0n = (long)(tt + 1) * 64;
            kn0 = *(const bf16x8*)&kb[(j0n + sr0) * 1536 + sg0 * 8];
            kn1 = *(const bf16x8*)&kb[(j0n + sr1) * 1536 + sg0 * 8];
            vn0 = *(const bf16x8*)&vb[(j0n + sr0) * 1536 + sg0 * 8];
            vn1 = *(const bf16x8*)&vb[(j0n + sr1) * 1536 + sg0 * 8];
        }
        const bf16_t* bt = bp + ((long)tt << 11);
        uint4 bv[4];
        bv[0] = *(const uint4*)(bt);
        bv[1] = *(const uint4*)(bt + 8);
        bv[2] = *(const uint4*)(bt + 1024);
        bv[3] = *(const uint4*)(bt + 1024 + 8);

#pragma unroll
        for (int js = 0; js < 2; ++js) {
            f32x16 s = {};
            const int krow = js * 32 + l31;
#pragma unroll
            for (int st = 0; st < 4; ++st) {
                bf16x8 kf = *(const bf16x8*)&k_lds[cur][krow * 64 +
                             (((st * 2 + hi) ^ (krow & 7)) << 3)];
                s = MFMA32(kf, qf[st], s);
            }
            bf16_t bb[16];
            *(uint4*)&bb[0] = bv[2 * js];
            *(uint4*)&bb[8] = bv[2 * js + 1];
            float sv[16];
#pragma unroll
            for (int r = 0; r < 16; ++r) sv[r] = s[r] + (float)bb[r];
            float mx = sv[0];
#pragma unroll
            for (int r = 1; r < 16; ++r) mx = fmaxf(mx, sv[r]);
            {
                float o0 = mx, o1 = mx;
                asm("" : "+v"(o1));
                asm("v_permlane32_swap_b32 %0, %1" : "+v"(o0), "+v"(o1));
                mx = fmaxf(o0, o1);
            }
            if (!__all(mx <= mrun + 11.0f)) {
                float mnew = fmaxf(mrun, mx);
                float al = __builtin_amdgcn_exp2f(mrun - mnew);
                mrun = mnew;
                lrun *= al;
#pragma unroll
                for (int r = 0; r < 16; ++r) {
                    oacc0[r] *= al;
                    oacc1[r] *= al;
                }
            }
            float s0 = 0.f, s1 = 0.f, s2 = 0.f, s3 = 0.f;
#pragma unroll
            for (int r = 0; r < 16; ++r) {
                sv[r] = __builtin_amdgcn_exp2f(sv[r] - mrun);
                if ((r & 3) == 0) s0 += sv[r];
                else if ((r & 3) == 1) s1 += sv[r];
                else if ((r & 3) == 2) s2 += sv[r];
                else s3 += sv[r];
            }
            float rs = (s0 + s1) + (s2 + s3);
            {
                float o0 = rs, o1 = rs;
                asm("" : "+v"(o1));
                asm("v_permlane32_swap_b32 %0, %1" : "+v"(o0), "+v"(o1));
                rs = o0 + o1;
            }
            lrun += rs;
            unsigned dw[8];
#pragma unroll
            for (int g = 0; g < 4; ++g) {
                unsigned da, db;
                asm("v_cvt_pk_bf16_f32 %0, %1, %2"
                    : "=v"(da) : "v"(sv[4 * g]), "v"(sv[4 * g + 1]));
                asm("v_cvt_pk_bf16_f32 %0, %1, %2"
                    : "=v"(db) : "v"(sv[4 * g + 2]), "v"(sv[4 * g + 3]));
                dw[2 * g] = da;
                dw[2 * g + 1] = db;
            }
#pragma unroll
            for (int kk = 0; kk < 2; ++kk) {
                asm("v_permlane32_swap_b32 %0, %1"
                    : "+v"(dw[4 * kk + 0]), "+v"(dw[4 * kk + 2]));
                asm("v_permlane32_swap_b32 %0, %1"
                    : "+v"(dw[4 * kk + 1]), "+v"(dw[4 * kk + 3]));
            }
#pragma unroll
            for (int kk = 0; kk < 2; ++kk) {
                u32x4 uv;
                uv[0] = dw[4 * kk + 0];
                uv[1] = dw[4 * kk + 1];
                uv[2] = dw[4 * kk + 2];
                uv[3] = dw[4 * kk + 3];
                bf16x8 pa = __builtin_bit_cast(bf16x8, uv);
#pragma unroll
                for (int db2 = 0; db2 < 2; ++db2) {
                    const int vrow = db2 * 32 + l31;
                    bf16x8 vf = *(const bf16x8*)&v_lds[cur][vrow * 64 +
                                 (((js * 4 + kk * 2 + hi) ^ (vrow & 7)) << 3)];
                    if (db2 == 0)
                        oacc0 = MFMA32(pa, vf, oacc0);
                    else
                        oacc1 = MFMA32(pa, vf, oacc1);
                }
            }
        }  // js
        if (tt < 15) {
            const int nb = cur ^ 1;
            *(bf16x8*)&k_lds[nb][sr0 * 64 + ((sg0 ^ (sr0 & 7)) << 3)] = kn0;
            *(bf16x8*)&k_lds[nb][sr1 * 64 + ((sg0 ^ (sr1 & 7)) << 3)] = kn1;
#pragma unroll
            for (int e = 0; e < 8; ++e) {
                int d0 = sg0 * 8 + e;
                v_lds[nb][d0 * 64 + (((sr0 >> 3) ^ (d0 & 7)) << 3) + (sr0 & 7)] =
                    vn0[e];
                v_lds[nb][d0 * 64 + (((sr1 >> 3) ^ (d0 & 7)) << 3) + (sr1 & 7)] =
                    vn1[e];
            }
        }
        __syncthreads();
    }

    float linv = 1.0f / lrun;
#pragma unroll
    for (int r = 0; r < 16; ++r) {
        int row = (r & 3) + 8 * (r >> 2) + 4 * hi;
        float lr = __int_as_float(
            __builtin_amdgcn_ds_bpermute(row << 2, __float_as_int(linv)));
        qb[(long)(q0w + row) * 1536 + l31] = (bf16_t)(oacc0[r] * lr);
        qb[(long)(q0w + row) * 1536 + 32 + l31] = (bf16_t)(oacc1[r] * lr);
    }
}

extern "C" void kernel_launch(void* const* d_in, const int* in_sizes, int n_in,
                              void* d_out, int out_size, void* d_ws,
                              size_t ws_size, hipStream_t stream) {
    const void* x = nullptr;
    const void* w_qkv = nullptr;
    const void* bias_table = nullptr;
    const void* w_out = nullptr;
    const void* b_out = nullptr;
    const void* rel_raw = nullptr;
    for (int i = 0; i < n_in; ++i) {
        switch (in_sizes[i]) {
            case 16777216: x = d_in[i]; break;
            case 786432:  w_qkv = d_in[i]; break;
            case 360:     bias_table = d_in[i]; break;
            case 262144:  w_out = d_in[i]; break;
            case 512:     b_out = d_in[i]; break;
            case 1048576: rel_raw = d_in[i]; break;
            default: break;
        }
    }
    if (!x || !w_qkv || !bias_table || !w_out || !b_out || !rel_raw) {
        x = d_in[0]; w_qkv = d_in[1]; bias_table = d_in[2];
        w_out = d_in[3]; b_out = d_in[4]; rel_raw = d_in[5];
    }
    const int* rel_index = (const int*)rel_raw;

    char* ws = (char*)d_ws;
    bf16_t* wqkvT = (bf16_t*)ws;                           // 1,572,864 B
    bf16_t* woutT = (bf16_t*)(ws + 1572864);               // 524,288 B
    int* flag = (int*)(ws + 1572864 + 524288);             // 256 B slot
    bf16_t* rel_bias = (bf16_t*)(ws + 1572864 + 524288 + 256);  // 16 MiB perm
    const size_t fixed = 1572864 + 524288 + 256 + 16777216;
    const size_t xbf_bytes = (size_t)32 * 1024 * 512 * sizeof(bf16_t);  // 32 MiB
    const size_t per_batch = (size_t)1024 * 1536 * sizeof(bf16_t);      // 3 MiB

    if (ws_size < fixed + per_batch) {
        long n = (long)out_size;
        long nblk = (n + 255) / 256;
        if (nblk > 0)
            zero_out<<<(unsigned)nblk, 256, 0, stream>>>(
                (unsigned short*)d_out, n);
        return;
    }

    // Prefer layout with x_bf (enables global_load_lds QKV gemm).
    bool have_xbf = ws_size >= fixed + xbf_bytes + per_batch;
    bf16_t* x_bf = (bf16_t*)(ws + fixed);
    bf16_t* qkv = have_xbf ? (bf16_t*)(ws + fixed + xbf_bytes)
                           : (bf16_t*)(ws + fixed);

    size_t avail = ws_size - fixed - (have_xbf ? xbf_bytes : 0);
    int chunk = (int)(avail / per_batch);
    if (chunk > 32) chunk = 32;
    if (chunk < 1) chunk = 1;
    while (32 % chunk) --chunk;

    detect_dtype<<<1, 64, 0, stream>>>((const unsigned*)x, flag);
    transpose_flex<<<dim3(1536 / 32, 512 / 32), dim3(32, 8), 0, stream>>>(
        w_qkv, wqkvT, 512, 1536, flag, 512);  // scale Q columns
    transpose_flex<<<dim3(512 / 32, 512 / 32), dim3(32, 8), 0, stream>>>(
        w_out, woutT, 512, 512, flag, 0);
    build_bias_perm<<<dim3(32, 32, 2), 256, 0, stream>>>(
        rel_index, bias_table, rel_bias, flag);
    if (have_xbf)
        convert_x<<<8192, 256, 0, stream>>>(x, x_bf, flag);

    for (int b0 = 0; b0 < 32; b0 += chunk) {
        long row0 = (long)b0 * 1024;
        int mrows = chunk * 1024;
        if (have_xbf) {
            gemm_lds<false, false>
                <<<dim3(1536 / 128, mrows / 128), 256, 0, stream>>>(
                    x_bf, wqkvT, 512, 512, row0, qkv, 1536, 0, nullptr, flag);
        } else {
            gemm128<true, false, false>
                <<<dim3(1536 / 128, mrows / 128), 256, 0, stream>>>(
                    x, wqkvT, 512, 512, row0, qkv, 1536, 0, nullptr, flag);
        }
        flash_attn2<<<dim3(8, 8, chunk), 256, 0, stream>>>(qkv, rel_bias);
        gemm_lds<true, true>
            <<<dim3(512 / 128, mrows / 128), 256, 0, stream>>>(
                qkv, woutT, 512, 1536, 0, d_out, 512, row0, b_out, flag);
    }
}

// Round 3
// 462.405 us; speedup vs baseline: 1.3581x; 1.0254x over previous
//
#include <hip/hip_runtime.h>
#include <hip/hip_bf16.h>
#include <cstdint>

typedef __bf16 bf16_t;
typedef bf16_t bf16x8 __attribute__((ext_vector_type(8)));
typedef float f32x4 __attribute__((ext_vector_type(4)));
typedef float f32x16 __attribute__((ext_vector_type(16)));
typedef unsigned u32x4 __attribute__((ext_vector_type(4)));

#define MFMA16(a, b, c) __builtin_amdgcn_mfma_f32_16x16x32_bf16(a, b, c, 0, 0, 0)
#define MFMA32(a, b, c) __builtin_amdgcn_mfma_f32_32x32x16_bf16(a, b, c, 0, 0, 0)

// async global->LDS, 16B per lane (ladder step 3; compiler never auto-emits)
#define GLOAD_LDS16(g, l)                                                  \
    __builtin_amdgcn_global_load_lds(                                      \
        (const __attribute__((address_space(1))) unsigned*)(g),            \
        (__attribute__((address_space(3))) unsigned*)(l), 16, 0, 0)

constexpr int LDK = 72;  // 64 + 8 pad (legacy gemm128 fallback)

// 0.125 (attn scale) * log2(e): folded into Q columns of w_qkv at transpose.
#define QSCALE 0.1803368801f
#define LOG2E 1.44269504f

__global__ void zero_out(unsigned short* __restrict__ out, long n) {
    long i = (long)blockIdx.x * 256 + threadIdx.x;
    if (i < n) out[i] = 0;
}

__global__ void detect_dtype(const unsigned* __restrict__ x,
                             int* __restrict__ flag) {
    if (threadIdx.x == 0 && blockIdx.x == 0) {
        int cnt = 0;
        for (int i = 0; i < 1024; ++i) {
            unsigned e = (x[i] >> 7) & 0xFF;
            cnt += (e > 100 && e < 150) ? 1 : 0;
        }
        *flag = (cnt > 512) ? 1 : 0;
    }
}

// x (fp32 or bf16 per flag) -> x_bf (bf16), vectorized.
__global__ __launch_bounds__(256) void convert_x(const void* __restrict__ in,
                                                 bf16_t* __restrict__ out,
                                                 const int* __restrict__ flagp) {
    const int fl = *flagp;
    long i = ((long)blockIdx.x * 256 + threadIdx.x) * 8;
    if (fl) {
        *(bf16x8*)&out[i] = *(const bf16x8*)&((const bf16_t*)in)[i];
    } else {
        f32x4 lo = *(const f32x4*)&((const float*)in)[i];
        f32x4 hi = *(const f32x4*)&((const float*)in)[i + 4];
        bf16x8 v;
#pragma unroll
        for (int e = 0; e < 4; ++e) {
            v[e] = (bf16_t)lo[e];
            v[e + 4] = (bf16_t)hi[e];
        }
        *(bf16x8*)&out[i] = v;
    }
}

// Transpose; rows of the OUTPUT with index < scale_rows get scaled by QSCALE
// (used to fold attn scale * log2e into the Q columns of w_qkv).
__global__ void transpose_flex(const void* __restrict__ in,
                               bf16_t* __restrict__ out, int R, int C,
                               const int* __restrict__ flagp, int scale_rows) {
    const int fl = *flagp;
    __shared__ bf16_t tile[32][33];
    int c0 = blockIdx.x * 32, r0 = blockIdx.y * 32;
    int x = threadIdx.x, y = threadIdx.y;  // 32 x 8
#pragma unroll
    for (int i = 0; i < 4; ++i) {
        long idx = (long)(r0 + y + 8 * i) * C + c0 + x;
        float fv = fl ? (float)((const bf16_t*)in)[idx]
                      : ((const float*)in)[idx];
        if (c0 + x < scale_rows) fv *= QSCALE;
        tile[y + 8 * i][x] = (bf16_t)fv;
    }
    __syncthreads();
#pragma unroll
    for (int i = 0; i < 4; ++i)
        out[(long)(c0 + y + 8 * i) * R + r0 + x] = tile[x][y + 8 * i];
}

// ---------------------------------------------------------------------------
// Bias pre-permuted into the 32x32 MFMA C-layout so flash reads it as two
// coalesced dwordx4 loads per lane per 32-j tile (no LDS, no scalar gathers).
// perm[h][qb][jt][lane][reg] = log2e * table[relidx[i*1024+j]][h]
//   i = qb*32 + (lane&31); j = jt*32 + (reg&3) + 8*(reg>>2) + 4*(lane>>5)
// ---------------------------------------------------------------------------
__global__ __launch_bounds__(256) void build_bias_perm(
    const int* __restrict__ rel_index, const void* __restrict__ bias_table,
    bf16_t* __restrict__ perm, const int* __restrict__ flagp) {
    const int fl = *flagp;
    const int jt = blockIdx.x;  // 0..31
    const int qb = blockIdx.y;  // 0..31
    const int t = threadIdx.x;
    const int lane = t & 63;
    const int h = (t >> 6) + 4 * blockIdx.z;  // 0..7
    const int i = qb * 32 + (lane & 31);
    const int hi = lane >> 5;
    bf16_t out[16];
#pragma unroll
    for (int r = 0; r < 16; ++r) {
        int j = jt * 32 + (r & 3) + 8 * (r >> 2) + 4 * hi;
        int ridx = rel_index[i * 1024 + j];
        ridx = ridx < 0 ? 0 : (ridx > 44 ? 44 : ridx);
        float bv = fl ? (float)((const bf16_t*)bias_table)[ridx * 8 + h]
                      : ((const float*)bias_table)[ridx * 8 + h];
        out[r] = (bf16_t)(bv * LOG2E);
    }
    long off = (((long)(h * 32 + qb) * 32 + jt) << 10) + lane * 16;
    *(uint4*)&perm[off] = *(uint4*)&out[0];
    *(uint4*)&perm[off + 8] = *(uint4*)&out[8];
}

// ---------------------------------------------------------------------------
// qkv V-part [b][j][1024 + h*64 + d] -> vt[(b*8+h)][d][1024 j].
// 64x64 tiles; LDS with row-bit XOR swizzle so both phases are vectorized
// and (near) conflict-free.
// ---------------------------------------------------------------------------
__global__ __launch_bounds__(256) void transpose_v(
    const bf16_t* __restrict__ qkv, bf16_t* __restrict__ vt) {
    __shared__ bf16_t tile[64 * 64];
    const int jt = blockIdx.x;  // 0..15
    const int bh = blockIdx.y;  // b*8+h (chunk-local)
    const int b = bh >> 3, h = bh & 7;
    const bf16_t* src = qkv + (long)b * 1024 * 1536 + 1024 + h * 64;
    const int t = threadIdx.x;
    const int r = t >> 3, c8 = t & 7;
    const int j0 = jt * 64;
#pragma unroll
    for (int rep = 0; rep < 2; ++rep) {
        int jj = r + 32 * rep;
        *(bf16x8*)&tile[jj * 64 + ((c8 ^ (jj >> 3)) << 3)] =
            *(const bf16x8*)&src[(long)(j0 + jj) * 1536 + c8 * 8];
    }
    __syncthreads();
#pragma unroll
    for (int rep = 0; rep < 2; ++rep) {
        int dd = r + 32 * rep;
        int jc = c8 * 8;
        bf16_t o[8];
#pragma unroll
        for (int e = 0; e < 8; ++e) {
            int row = jc + e;
            o[e] = tile[row * 64 + (((dd >> 3) ^ (row >> 3)) << 3) + (dd & 7)];
        }
        *(bf16x8*)&vt[((long)bh << 16) + (long)dd * 1024 + j0 + jc] =
            *(bf16x8*)&o[0];
    }
}

// ---------------------------------------------------------------------------
// m97-structure GEMM: bf16 A and Bt, global_load_lds (width=16) staging into
// linear [128][64] LDS, 2 barriers per K-step.
// C[(c_row0+m)][n] = sum_k A[(a_row0+m)][k] * Bt[n][k]  (+ bias[n])
// ---------------------------------------------------------------------------
template <bool BIAS, bool OUTFLEX>
__global__ __launch_bounds__(256) void gemm_lds(
    const bf16_t* __restrict__ A, const bf16_t* __restrict__ Bt, int K,
    int lda, long a_row0, void* __restrict__ C, int ldc, long c_row0,
    const void* __restrict__ bias, const int* __restrict__ flagp) {
    const int fl = *flagp;
    __shared__ bf16_t a_lds[128 * 64];
    __shared__ bf16_t b_lds[128 * 64];
    int t = threadIdx.x;
    int wave = t >> 6, lane = t & 63;
    int m16 = lane & 15, quad = lane >> 4;
    int wr = wave >> 1, wc = wave & 1;
    long m0 = (long)blockIdx.y * 128;
    int n0 = blockIdx.x * 128;

    f32x4 acc[4][4] = {};

    for (int ks = 0; ks < K; ks += 64) {
#pragma unroll
        for (int i = 0; i < 4; ++i) {
            int c = wave * 256 + i * 64 + lane;
            int row = c >> 3, kc = (c & 7) << 3;
            GLOAD_LDS16(&A[(a_row0 + m0 + row) * (long)lda + ks + kc],
                        &a_lds[row * 64 + kc]);
            GLOAD_LDS16(&Bt[(long)(n0 + row) * K + ks + kc],
                        &b_lds[row * 64 + kc]);
        }
        __syncthreads();
#pragma unroll
        for (int kf = 0; kf < 2; ++kf) {
            bf16x8 af[4], bfr[4];
#pragma unroll
            for (int mb = 0; mb < 4; ++mb)
                af[mb] = *(const bf16x8*)&a_lds[(wr * 64 + mb * 16 + m16) * 64 +
                                                kf * 32 + quad * 8];
#pragma unroll
            for (int nb = 0; nb < 4; ++nb)
                bfr[nb] = *(const bf16x8*)&b_lds[(wc * 64 + nb * 16 + m16) * 64 +
                                                 kf * 32 + quad * 8];
#pragma unroll
            for (int mb = 0; mb < 4; ++mb)
#pragma unroll
                for (int nb = 0; nb < 4; ++nb)
                    acc[mb][nb] = MFMA16(af[mb], bfr[nb], acc[mb][nb]);
        }
        __syncthreads();
    }

#pragma unroll
    for (int mb = 0; mb < 4; ++mb) {
#pragma unroll
        for (int nb = 0; nb < 4; ++nb) {
            int col = n0 + wc * 64 + nb * 16 + m16;
#pragma unroll
            for (int r = 0; r < 4; ++r) {
                long row = m0 + wr * 64 + mb * 16 + quad * 4 + r;
                float v = acc[mb][nb][r];
                if (BIAS) {
                    float bb = fl ? (float)((const bf16_t*)bias)[col]
                                  : ((const float*)bias)[col];
                    v += bb;
                }
                long off = (c_row0 + row) * (long)ldc + col;
                if (OUTFLEX && !fl)
                    ((float*)C)[off] = v;
                else
                    ((bf16_t*)C)[off] = (bf16_t)v;
            }
        }
    }
}

// Legacy register-staged flex GEMM (fallback when ws can't hold x_bf).
template <bool AFLEX, bool BIAS, bool OUTFLEX>
__global__ __launch_bounds__(256) void gemm128(
    const void* __restrict__ A, const bf16_t* __restrict__ Bt, int K, int lda,
    long a_row0, void* __restrict__ C, int ldc, long c_row0,
    const void* __restrict__ bias, const int* __restrict__ flagp) {
    const int fl = *flagp;
    __shared__ bf16_t a_lds[128 * LDK];
    __shared__ bf16_t b_lds[128 * LDK];
    int t = threadIdx.x;
    int wave = t >> 6, lane = t & 63;
    int m16 = lane & 15, quad = lane >> 4;
    int wr = wave >> 1, wc = wave & 1;
    long m0 = (long)blockIdx.y * 128;
    int n0 = blockIdx.x * 128;

    f32x4 acc[4][4] = {};

    for (int ks = 0; ks < K; ks += 64) {
#pragma unroll
        for (int i = 0; i < 4; ++i) {
            int c = t + 256 * i;
            int row = c >> 3;
            int kc = (c & 7) << 3;
            bf16x8 av;
            if (AFLEX && !fl) {
                const float* Af = (const float*)A;
                long base = (a_row0 + m0 + row) * (long)lda + ks + kc;
                f32x4 lo = *(const f32x4*)&Af[base];
                f32x4 hi = *(const f32x4*)&Af[base + 4];
#pragma unroll
                for (int e = 0; e < 4; ++e) {
                    av[e] = (bf16_t)lo[e];
                    av[e + 4] = (bf16_t)hi[e];
                }
            } else {
                av = *(const bf16x8*)&(
                    (const bf16_t*)A)[(a_row0 + m0 + row) * (long)lda + ks + kc];
            }
            *(bf16x8*)&a_lds[row * LDK + kc] = av;
            *(bf16x8*)&b_lds[row * LDK + kc] =
                *(const bf16x8*)&Bt[(long)(n0 + row) * K + ks + kc];
        }
        __syncthreads();
#pragma unroll
        for (int kf = 0; kf < 2; ++kf) {
            bf16x8 af[4], bfr[4];
#pragma unroll
            for (int mb = 0; mb < 4; ++mb)
                af[mb] = *(const bf16x8*)&a_lds[(wr * 64 + mb * 16 + m16) * LDK +
                                                kf * 32 + quad * 8];
#pragma unroll
            for (int nb = 0; nb < 4; ++nb)
                bfr[nb] = *(const bf16x8*)&b_lds[(wc * 64 + nb * 16 + m16) * LDK +
                                                 kf * 32 + quad * 8];
#pragma unroll
            for (int mb = 0; mb < 4; ++mb)
#pragma unroll
                for (int nb = 0; nb < 4; ++nb)
                    acc[mb][nb] = MFMA16(af[mb], bfr[nb], acc[mb][nb]);
        }
        __syncthreads();
    }

#pragma unroll
    for (int mb = 0; mb < 4; ++mb) {
#pragma unroll
        for (int nb = 0; nb < 4; ++nb) {
            int col = n0 + wc * 64 + nb * 16 + m16;
#pragma unroll
            for (int r = 0; r < 4; ++r) {
                long row = m0 + wr * 64 + mb * 16 + quad * 4 + r;
                float v = acc[mb][nb][r];
                if (BIAS) {
                    float bb = fl ? (float)((const bf16_t*)bias)[col]
                                  : ((const float*)bias)[col];
                    v += bb;
                }
                long off = (c_row0 + row) * (long)ldc + col;
                if (OUTFLEX && !fl)
                    ((float*)C)[off] = v;
                else
                    ((bf16_t*)C)[off] = (bf16_t)v;
            }
        }
    }
}

// ---------------------------------------------------------------------------
// Flash attention v3: swapped-operand 32x32x16 MFMA, lane-local softmax,
// K and V^T both staged via global_load_lds (width=16) with pre-swizzled
// global source (linear LDS dest, swizzled read) — m97/m173 pattern.
// One barrier per 64-j tile; next tile's loads issued at tile top (after
// bias loads so bias consume waits vmcnt(4), keeping the DMA in flight).
// ---------------------------------------------------------------------------
__global__ __launch_bounds__(256) void flash_attn3(
    bf16_t* __restrict__ qkv, const bf16_t* __restrict__ vt,
    const bf16_t* __restrict__ bias_perm) {
    __shared__ bf16_t k_lds[2][64 * 64];
    __shared__ bf16_t v_lds[2][64 * 64];

    const int t = threadIdx.x;
    const int lane = t & 63, wave = t >> 6;
    const int l31 = lane & 31, hi = lane >> 5;
    const int h = blockIdx.y, b = blockIdx.z;
    bf16_t* base = qkv + (long)b * 1024 * 1536;
    bf16_t* qb = base + h * 64;
    const bf16_t* kb = base + 512 + h * 64;
    const bf16_t* vtb = vt + ((long)(b * 8 + h) << 16);
    const int qblk = blockIdx.x * 4 + wave;  // 0..31
    const int q0w = qblk * 32;
    const bf16_t* bp = bias_perm + (((long)(h * 32 + qblk)) << 15) + lane * 16;

    // Q fragments (already scaled by 0.125*log2e): B-operand rows = q
    bf16x8 qf[4];
#pragma unroll
    for (int s = 0; s < 4; ++s)
        qf[s] = *(const bf16x8*)&qb[(long)(q0w + l31) * 1536 + s * 16 + hi * 8];

    f32x16 oacc0 = {}, oacc1 = {};
    float mrun = -1e30f, lrun = 0.f;

    // staging: row = t>>3 (and +32), phys chunk pc = t&7.
    // source chunk offset = (pc ^ (row&7))*8 ; (row+32)&7 == row&7.
    const int srow = t >> 3, pc = t & 7;
    const int kc0 = (pc ^ (srow & 7)) << 3;

    {  // prologue: stage tile 0 (async DMA, drained by the barrier)
        GLOAD_LDS16(&kb[(long)srow * 1536 + kc0],
                    &k_lds[0][srow * 64 + pc * 8]);
        GLOAD_LDS16(&kb[(long)(srow + 32) * 1536 + kc0],
                    &k_lds[0][(srow + 32) * 64 + pc * 8]);
        GLOAD_LDS16(&vtb[(long)srow * 1024 + kc0],
                    &v_lds[0][srow * 64 + pc * 8]);
        GLOAD_LDS16(&vtb[(long)(srow + 32) * 1024 + kc0],
                    &v_lds[0][(srow + 32) * 64 + pc * 8]);
    }
    __syncthreads();

    for (int tt = 0; tt < 16; ++tt) {
        const int cur = tt & 1;
        // bias loads FIRST (so their waitcnt is vmcnt(4), not 0)
        const bf16_t* bt = bp + ((long)tt << 11);
        uint4 bv[4];
        bv[0] = *(const uint4*)(bt);
        bv[1] = *(const uint4*)(bt + 8);
        bv[2] = *(const uint4*)(bt + 1024);
        bv[3] = *(const uint4*)(bt + 1024 + 8);
        if (tt < 15) {  // issue next tile's DMA; drains at end-of-tile barrier
            const int nb = cur ^ 1;
            long j0n = (long)(tt + 1) * 64;
            GLOAD_LDS16(&kb[(j0n + srow) * 1536 + kc0],
                        &k_lds[nb][srow * 64 + pc * 8]);
            GLOAD_LDS16(&kb[(j0n + srow + 32) * 1536 + kc0],
                        &k_lds[nb][(srow + 32) * 64 + pc * 8]);
            GLOAD_LDS16(&vtb[(long)srow * 1024 + j0n + kc0],
                        &v_lds[nb][srow * 64 + pc * 8]);
            GLOAD_LDS16(&vtb[(long)(srow + 32) * 1024 + j0n + kc0],
                        &v_lds[nb][(srow + 32) * 64 + pc * 8]);
        }

#pragma unroll
        for (int js = 0; js < 2; ++js) {
            // ---- S^T = K Q^T : lane owns q-row (col = l31) ----
            f32x16 s = {};
            const int krow = js * 32 + l31;
#pragma unroll
            for (int st = 0; st < 4; ++st) {
                bf16x8 kf = *(const bf16x8*)&k_lds[cur][krow * 64 +
                             (((st * 2 + hi) ^ (krow & 7)) << 3)];
                s = MFMA32(kf, qf[st], s);
            }
            // ---- + bias (already log2e-scaled, layout-matched) ----
            bf16_t bb[16];
            *(uint4*)&bb[0] = bv[2 * js];
            *(uint4*)&bb[8] = bv[2 * js + 1];
            float sv[16];
#pragma unroll
            for (int r = 0; r < 16; ++r) sv[r] = s[r] + (float)bb[r];
            // ---- row max: in-lane tree + one cross-half swap ----
            float mx = sv[0];
#pragma unroll
            for (int r = 1; r < 16; ++r) mx = fmaxf(mx, sv[r]);
            {
                float o0 = mx, o1 = mx;
                asm("" : "+v"(o1));
                asm("v_permlane32_swap_b32 %0, %1" : "+v"(o0), "+v"(o1));
                mx = fmaxf(o0, o1);
            }
            // ---- defer-max rescale (THR=11 in log2 units) ----
            if (!__all(mx <= mrun + 11.0f)) {
                float mnew = fmaxf(mrun, mx);
                float al = __builtin_amdgcn_exp2f(mrun - mnew);
                mrun = mnew;
                lrun *= al;
#pragma unroll
                for (int r = 0; r < 16; ++r) {
                    oacc0[r] *= al;
                    oacc1[r] *= al;
                }
            }
            // ---- P = 2^(S-m), row sum ----
            float s0 = 0.f, s1 = 0.f, s2 = 0.f, s3 = 0.f;
#pragma unroll
            for (int r = 0; r < 16; ++r) {
                sv[r] = __builtin_amdgcn_exp2f(sv[r] - mrun);
                if ((r & 3) == 0) s0 += sv[r];
                else if ((r & 3) == 1) s1 += sv[r];
                else if ((r & 3) == 2) s2 += sv[r];
                else s3 += sv[r];
            }
            float rs = (s0 + s1) + (s2 + s3);
            {
                float o0 = rs, o1 = rs;
                asm("" : "+v"(o1));
                asm("v_permlane32_swap_b32 %0, %1" : "+v"(o0), "+v"(o1));
                rs = o0 + o1;
            }
            lrun += rs;
            // ---- repack P^T (C-layout) -> PV A-fragments, in-register ----
            unsigned dw[8];
#pragma unroll
            for (int g = 0; g < 4; ++g) {
                unsigned da, db;
                asm("v_cvt_pk_bf16_f32 %0, %1, %2"
                    : "=v"(da) : "v"(sv[4 * g]), "v"(sv[4 * g + 1]));
                asm("v_cvt_pk_bf16_f32 %0, %1, %2"
                    : "=v"(db) : "v"(sv[4 * g + 2]), "v"(sv[4 * g + 3]));
                dw[2 * g] = da;
                dw[2 * g + 1] = db;
            }
#pragma unroll
            for (int kk = 0; kk < 2; ++kk) {
                asm("v_permlane32_swap_b32 %0, %1"
                    : "+v"(dw[4 * kk + 0]), "+v"(dw[4 * kk + 2]));
                asm("v_permlane32_swap_b32 %0, %1"
                    : "+v"(dw[4 * kk + 1]), "+v"(dw[4 * kk + 3]));
            }
            // ---- O += P V (rows=q, cols=d) ----
#pragma unroll
            for (int kk = 0; kk < 2; ++kk) {
                u32x4 uv;
                uv[0] = dw[4 * kk + 0];
                uv[1] = dw[4 * kk + 1];
                uv[2] = dw[4 * kk + 2];
                uv[3] = dw[4 * kk + 3];
                bf16x8 pa = __builtin_bit_cast(bf16x8, uv);
#pragma unroll
                for (int db2 = 0; db2 < 2; ++db2) {
                    const int vrow = db2 * 32 + l31;
                    bf16x8 vf = *(const bf16x8*)&v_lds[cur][vrow * 64 +
                                 (((js * 4 + kk * 2 + hi) ^ (vrow & 7)) << 3)];
                    if (db2 == 0)
                        oacc0 = MFMA32(pa, vf, oacc0);
                    else
                        oacc1 = MFMA32(pa, vf, oacc1);
                }
            }
        }  // js
        __syncthreads();  // drains next-tile DMA + guards buffer swap
    }

    // ---- epilogue: O[i][d] / l[i]; 1/l broadcast via ds_bpermute ----
    float linv = 1.0f / lrun;
#pragma unroll
    for (int r = 0; r < 16; ++r) {
        int row = (r & 3) + 8 * (r >> 2) + 4 * hi;
        float lr = __int_as_float(
            __builtin_amdgcn_ds_bpermute(row << 2, __float_as_int(linv)));
        qb[(long)(q0w + row) * 1536 + l31] = (bf16_t)(oacc0[r] * lr);
        qb[(long)(q0w + row) * 1536 + 32 + l31] = (bf16_t)(oacc1[r] * lr);
    }
}

// Fallback flash (reg-staged, in-flash V transpose) for small workspaces.
__global__ __launch_bounds__(256) void flash_attn2(
    bf16_t* __restrict__ qkv, const bf16_t* __restrict__ bias_perm) {
    __shared__ bf16_t k_lds[2][64 * 64];
    __shared__ bf16_t v_lds[2][64 * 64];

    const int t = threadIdx.x;
    const int lane = t & 63, wave = t >> 6;
    const int l31 = lane & 31, hi = lane >> 5;
    const int h = blockIdx.y, b = blockIdx.z;
    bf16_t* base = qkv + (long)b * 1024 * 1536;
    bf16_t* qb = base + h * 64;
    const bf16_t* kb = base + 512 + h * 64;
    const bf16_t* vb = base + 1024 + h * 64;
    const int qblk = blockIdx.x * 4 + wave;
    const int q0w = qblk * 32;
    const bf16_t* bp = bias_perm + (((long)(h * 32 + qblk)) << 15) + lane * 16;

    bf16x8 qf[4];
#pragma unroll
    for (int s = 0; s < 4; ++s)
        qf[s] = *(const bf16x8*)&qb[(long)(q0w + l31) * 1536 + s * 16 + hi * 8];

    f32x16 oacc0 = {}, oacc1 = {};
    float mrun = -1e30f, lrun = 0.f;

    const int sr0 = t >> 3, sg0 = t & 7;
    const int sr1 = sr0 + 32;

    {
        bf16x8 k0 = *(const bf16x8*)&kb[(long)sr0 * 1536 + sg0 * 8];
        bf16x8 k1 = *(const bf16x8*)&kb[(long)sr1 * 1536 + sg0 * 8];
        bf16x8 v0 = *(const bf16x8*)&vb[(long)sr0 * 1536 + sg0 * 8];
        bf16x8 v1 = *(const bf16x8*)&vb[(long)sr1 * 1536 + sg0 * 8];
        *(bf16x8*)&k_lds[0][sr0 * 64 + ((sg0 ^ (sr0 & 7)) << 3)] = k0;
        *(bf16x8*)&k_lds[0][sr1 * 64 + ((sg0 ^ (sr1 & 7)) << 3)] = k1;
#pragma unroll
        for (int e = 0; e < 8; ++e) {
            int d0 = sg0 * 8 + e;
            v_lds[0][d0 * 64 + (((sr0 >> 3) ^ (d0 & 7)) << 3) + (sr0 & 7)] = v0[e];
            v_lds[0][d0 * 64 + (((sr1 >> 3) ^ (d0 & 7)) << 3) + (sr1 & 7)] = v1[e];
        }
    }
    __syncthreads();

    for (int tt = 0; tt < 16; ++tt) {
        const int cur = tt & 1;
        bf16x8 kn0 = {}, kn1 = {}, vn0 = {}, vn1 = {};
        if (tt < 15) {
            long j0n = (long)(tt + 1) * 64;
            kn0 = *(const bf16x8*)&kb[(j0n + sr0) * 1536 + sg0 * 8];
            kn1 = *(const bf16x8*)&kb[(j0n + sr1) * 1536 + sg0 * 8];
            vn0 = *(const bf16x8*)&vb[(j0n + sr0) * 1536 + sg0 * 8];
            vn1 = *(const bf16x8*)&vb[(j0n + sr1) * 1536 + sg0 * 8];
        }
        const bf16_t* bt = bp + ((long)tt << 11);
        uint4 bv[4];
        bv[0] = *(const uint4*)(bt);
        bv[1] = *(const uint4*)(bt + 8);
        bv[2] = *(const uint4*)(bt + 1024);
        bv[3] = *(const uint4*)(bt + 1024 + 8);

#pragma unroll
        for (int js = 0; js < 2; ++js) {
            f32x16 s = {};
            const int krow = js * 32 + l31;
#pragma unroll
            for (int st = 0; st < 4; ++st) {
                bf16x8 kf = *(const bf16x8*)&k_lds[cur][krow * 64 +
                             (((st * 2 + hi) ^ (krow & 7)) << 3)];
                s = MFMA32(kf, qf[st], s);
            }
            bf16_t bb[16];
            *(uint4*)&bb[0] = bv[2 * js];
            *(uint4*)&bb[8] = bv[2 * js + 1];
            float sv[16];
#pragma unroll
            for (int r = 0; r < 16; ++r) sv[r] = s[r] + (float)bb[r];
            float mx = sv[0];
#pragma unroll
            for (int r = 1; r < 16; ++r) mx = fmaxf(mx, sv[r]);
            {
                float o0 = mx, o1 = mx;
                asm("" : "+v"(o1));
                asm("v_permlane32_swap_b32 %0, %1" : "+v"(o0), "+v"(o1));
                mx = fmaxf(o0, o1);
            }
            if (!__all(mx <= mrun + 11.0f)) {
                float mnew = fmaxf(mrun, mx);
                float al = __builtin_amdgcn_exp2f(mrun - mnew);
                mrun = mnew;
                lrun *= al;
#pragma unroll
                for (int r = 0; r < 16; ++r) {
                    oacc0[r] *= al;
                    oacc1[r] *= al;
                }
            }
            float s0 = 0.f, s1 = 0.f, s2 = 0.f, s3 = 0.f;
#pragma unroll
            for (int r = 0; r < 16; ++r) {
                sv[r] = __builtin_amdgcn_exp2f(sv[r] - mrun);
                if ((r & 3) == 0) s0 += sv[r];
                else if ((r & 3) == 1) s1 += sv[r];
                else if ((r & 3) == 2) s2 += sv[r];
                else s3 += sv[r];
            }
            float rs = (s0 + s1) + (s2 + s3);
            {
                float o0 = rs, o1 = rs;
                asm("" : "+v"(o1));
                asm("v_permlane32_swap_b32 %0, %1" : "+v"(o0), "+v"(o1));
                rs = o0 + o1;
            }
            lrun += rs;
            unsigned dw[8];
#pragma unroll
            for (int g = 0; g < 4; ++g) {
                unsigned da, db;
                asm("v_cvt_pk_bf16_f32 %0, %1, %2"
                    : "=v"(da) : "v"(sv[4 * g]), "v"(sv[4 * g + 1]));
                asm("v_cvt_pk_bf16_f32 %0, %1, %2"
                    : "=v"(db) : "v"(sv[4 * g + 2]), "v"(sv[4 * g + 3]));
                dw[2 * g] = da;
                dw[2 * g + 1] = db;
            }
#pragma unroll
            for (int kk = 0; kk < 2; ++kk) {
                asm("v_permlane32_swap_b32 %0, %1"
                    : "+v"(dw[4 * kk + 0]), "+v"(dw[4 * kk + 2]));
                asm("v_permlane32_swap_b32 %0, %1"
                    : "+v"(dw[4 * kk + 1]), "+v"(dw[4 * kk + 3]));
            }
#pragma unroll
            for (int kk = 0; kk < 2; ++kk) {
                u32x4 uv;
                uv[0] = dw[4 * kk + 0];
                uv[1] = dw[4 * kk + 1];
                uv[2] = dw[4 * kk + 2];
                uv[3] = dw[4 * kk + 3];
                bf16x8 pa = __builtin_bit_cast(bf16x8, uv);
#pragma unroll
                for (int db2 = 0; db2 < 2; ++db2) {
                    const int vrow = db2 * 32 + l31;
                    bf16x8 vf = *(const bf16x8*)&v_lds[cur][vrow * 64 +
                                 (((js * 4 + kk * 2 + hi) ^ (vrow & 7)) << 3)];
                    if (db2 == 0)
                        oacc0 = MFMA32(pa, vf, oacc0);
                    else
                        oacc1 = MFMA32(pa, vf, oacc1);
                }
            }
        }
        if (tt < 15) {
            const int nb = cur ^ 1;
            *(bf16x8*)&k_lds[nb][sr0 * 64 + ((sg0 ^ (sr0 & 7)) << 3)] = kn0;
            *(bf16x8*)&k_lds[nb][sr1 * 64 + ((sg0 ^ (sr1 & 7)) << 3)] = kn1;
#pragma unroll
            for (int e = 0; e < 8; ++e) {
                int d0 = sg0 * 8 + e;
                v_lds[nb][d0 * 64 + (((sr0 >> 3) ^ (d0 & 7)) << 3) + (sr0 & 7)] =
                    vn0[e];
                v_lds[nb][d0 * 64 + (((sr1 >> 3) ^ (d0 & 7)) << 3) + (sr1 & 7)] =
                    vn1[e];
            }
        }
        __syncthreads();
    }

    float linv = 1.0f / lrun;
#pragma unroll
    for (int r = 0; r < 16; ++r) {
        int row = (r & 3) + 8 * (r >> 2) + 4 * hi;
        float lr = __int_as_float(
            __builtin_amdgcn_ds_bpermute(row << 2, __float_as_int(linv)));
        qb[(long)(q0w + row) * 1536 + l31] = (bf16_t)(oacc0[r] * lr);
        qb[(long)(q0w + row) * 1536 + 32 + l31] = (bf16_t)(oacc1[r] * lr);
    }
}

extern "C" void kernel_launch(void* const* d_in, const int* in_sizes, int n_in,
                              void* d_out, int out_size, void* d_ws,
                              size_t ws_size, hipStream_t stream) {
    const void* x = nullptr;
    const void* w_qkv = nullptr;
    const void* bias_table = nullptr;
    const void* w_out = nullptr;
    const void* b_out = nullptr;
    const void* rel_raw = nullptr;
    for (int i = 0; i < n_in; ++i) {
        switch (in_sizes[i]) {
            case 16777216: x = d_in[i]; break;
            case 786432:  w_qkv = d_in[i]; break;
            case 360:     bias_table = d_in[i]; break;
            case 262144:  w_out = d_in[i]; break;
            case 512:     b_out = d_in[i]; break;
            case 1048576: rel_raw = d_in[i]; break;
            default: break;
        }
    }
    if (!x || !w_qkv || !bias_table || !w_out || !b_out || !rel_raw) {
        x = d_in[0]; w_qkv = d_in[1]; bias_table = d_in[2];
        w_out = d_in[3]; b_out = d_in[4]; rel_raw = d_in[5];
    }
    const int* rel_index = (const int*)rel_raw;

    char* ws = (char*)d_ws;
    bf16_t* wqkvT = (bf16_t*)ws;                           // 1,572,864 B
    bf16_t* woutT = (bf16_t*)(ws + 1572864);               // 524,288 B
    int* flag = (int*)(ws + 1572864 + 524288);             // 256 B slot
    bf16_t* rel_bias = (bf16_t*)(ws + 1572864 + 524288 + 256);  // 16 MiB perm
    const size_t fixed = 1572864 + 524288 + 256 + 16777216;
    const size_t xbf_bytes = (size_t)32 * 1024 * 512 * sizeof(bf16_t);  // 32 MiB
    const size_t qkv_pb = (size_t)1024 * 1536 * sizeof(bf16_t);  // 3 MiB
    const size_t vt_pb = (size_t)8 * 64 * 1024 * sizeof(bf16_t); // 1 MiB

    if (ws_size < fixed + qkv_pb) {
        long n = (long)out_size;
        long nblk = (n + 255) / 256;
        if (nblk > 0)
            zero_out<<<(unsigned)nblk, 256, 0, stream>>>(
                (unsigned short*)d_out, n);
        return;
    }

    bool have_xbf = ws_size >= fixed + xbf_bytes + qkv_pb;
    bool have_vt = ws_size >= fixed + xbf_bytes + qkv_pb + vt_pb;
    bf16_t* x_bf = (bf16_t*)(ws + fixed);
    bf16_t* qkv = have_xbf ? (bf16_t*)(ws + fixed + xbf_bytes)
                           : (bf16_t*)(ws + fixed);

    size_t avail = ws_size - fixed - (have_xbf ? xbf_bytes : 0);
    size_t pb = have_vt ? (qkv_pb + vt_pb) : qkv_pb;
    int chunk = (int)(avail / pb);
    if (chunk > 32) chunk = 32;
    if (chunk < 1) chunk = 1;
    while (32 % chunk) --chunk;
    bf16_t* vt = (bf16_t*)((char*)qkv + (size_t)chunk * qkv_pb);

    detect_dtype<<<1, 64, 0, stream>>>((const unsigned*)x, flag);
    transpose_flex<<<dim3(1536 / 32, 512 / 32), dim3(32, 8), 0, stream>>>(
        w_qkv, wqkvT, 512, 1536, flag, 512);  // scale Q columns
    transpose_flex<<<dim3(512 / 32, 512 / 32), dim3(32, 8), 0, stream>>>(
        w_out, woutT, 512, 512, flag, 0);
    build_bias_perm<<<dim3(32, 32, 2), 256, 0, stream>>>(
        rel_index, bias_table, rel_bias, flag);
    if (have_xbf)
        convert_x<<<8192, 256, 0, stream>>>(x, x_bf, flag);

    for (int b0 = 0; b0 < 32; b0 += chunk) {
        long row0 = (long)b0 * 1024;
        int mrows = chunk * 1024;
        if (have_xbf) {
            gemm_lds<false, false>
                <<<dim3(1536 / 128, mrows / 128), 256, 0, stream>>>(
                    x_bf, wqkvT, 512, 512, row0, qkv, 1536, 0, nullptr, flag);
        } else {
            gemm128<true, false, false>
                <<<dim3(1536 / 128, mrows / 128), 256, 0, stream>>>(
                    x, wqkvT, 512, 512, row0, qkv, 1536, 0, nullptr, flag);
        }
        if (have_vt) {
            transpose_v<<<dim3(16, chunk * 8), 256, 0, stream>>>(qkv, vt);
            flash_attn3<<<dim3(8, 8, chunk), 256, 0, stream>>>(qkv, vt,
                                                               rel_bias);
        } else {
            flash_attn2<<<dim3(8, 8, chunk), 256, 0, stream>>>(qkv, rel_bias);
        }
        gemm_lds<true, true>
            <<<dim3(512 / 128, mrows / 128), 256, 0, stream>>>(
                qkv, woutT, 512, 1536, 0, d_out, 512, row0, b_out, flag);
    }
}